// Round 1
// baseline (129.772 us; speedup 1.0000x reference)
//
#include <hip/hip_runtime.h>

#define BUCKETS_MASK ((1u << 21) - 1u)
#define RES_F 0.025f
#define DIMS 32

__global__ __launch_bounds__(256) void infer_hashgrid_kernel(
    const float* __restrict__ pts,
    const float* __restrict__ vf,
    const int* __restrict__ hash2vox,
    const float* __restrict__ smin,
    float* __restrict__ out,
    int n_pts)
{
    const unsigned P0 = 1u, P1 = 2654435761u, P2 = 805459861u;

    int tid = blockIdx.x * blockDim.x + threadIdx.x;
    int pt = tid >> 5;          // 32 lanes per point
    int d  = tid & 31;          // feature channel
    if (pt >= n_pts) return;

    float sx = smin[0], sy = smin[1], sz = smin[2];
    float px = pts[pt * 3 + 0];
    float py = pts[pt * 3 + 1];
    float pz = pts[pt * 3 + 2];

    // IEEE float32 division to bit-match numpy's (pts - smin)/RES before floor
    float qx = (px - sx) / RES_F;
    float qy = (py - sy) / RES_F;
    float qz = (pz - sz) / RES_F;

    float bx = floorf(qx), by = floorf(qy), bz = floorf(qz);
    float fx = qx - bx, fy = qy - by, fz = qz - bz;

    unsigned ix = (unsigned)bx;
    unsigned iy = (unsigned)by;
    unsigned iz = (unsigned)bz;

    unsigned h000 = ix * P0 + iy * P1 + iz * P2;   // uint32 wraparound == numpy

    float wx[2] = {1.0f - fx, fx};
    float wy[2] = {1.0f - fy, fy};
    float wz[2] = {1.0f - fz, fz};

    float acc = 0.0f;

#pragma unroll
    for (int c = 0; c < 8; ++c) {
        unsigned cx = c & 1u;
        unsigned cy = (c >> 1) & 1u;
        unsigned cz = (c >> 2) & 1u;
        unsigned hv = (h000 + (cx ? P0 : 0u) + (cy ? P1 : 0u) + (cz ? P2 : 0u)) & BUCKETS_MASK;
        int vid = hash2vox[hv];          // wave-uniform within the 32-lane group
        float w = wx[cx] * wy[cy] * wz[cz];
        float f = 0.0f;
        if (vid >= 0) {
            f = vf[(size_t)vid * DIMS + d];  // 128B coalesced line per corner
        }
        acc += f * w;
    }

    out[(size_t)pt * DIMS + d] = acc;
}

extern "C" void kernel_launch(void* const* d_in, const int* in_sizes, int n_in,
                              void* d_out, int out_size, void* d_ws, size_t ws_size,
                              hipStream_t stream) {
    const float* pts      = (const float*)d_in[0];
    const float* vf       = (const float*)d_in[1];
    const int*   hash2vox = (const int*)d_in[2];
    const float* smin     = (const float*)d_in[3];
    float* out = (float*)d_out;

    int n_pts = in_sizes[0] / 3;
    int total_threads = n_pts * 32;
    int block = 256;
    int grid = (total_threads + block - 1) / block;

    infer_hashgrid_kernel<<<grid, block, 0, stream>>>(pts, vf, hash2vox, smin, out, n_pts);
}

// Round 2
// 76.799 us; speedup vs baseline: 1.6898x; 1.6898x over previous
//
#include <hip/hip_runtime.h>

#define BUCKETS_MASK ((1u << 21) - 1u)
#define RES_F 0.025f
#define DIMS 32

__global__ __launch_bounds__(256) void infer_hashgrid_kernel(
    const float* __restrict__ pts,
    const float4* __restrict__ vf4,     // voxel_features viewed as [V][8] float4
    const int* __restrict__ hash2vox,
    const float* __restrict__ smin,
    float4* __restrict__ out4,          // out viewed as [N][8] float4
    int n_pts)
{
    const unsigned P0 = 1u, P1 = 2654435761u, P2 = 805459861u;

    int tid = blockIdx.x * blockDim.x + threadIdx.x;
    int pt = tid >> 3;          // 8 lanes per point
    int dq = tid & 7;           // which float4 of the 32-dim feature row
    if (pt >= n_pts) return;

    float sx = smin[0], sy = smin[1], sz = smin[2];
    float px = pts[pt * 3 + 0];
    float py = pts[pt * 3 + 1];
    float pz = pts[pt * 3 + 2];

    // IEEE float32 division to bit-match numpy's (pts - smin)/RES before floor
    float qx = (px - sx) / RES_F;
    float qy = (py - sy) / RES_F;
    float qz = (pz - sz) / RES_F;

    float bx = floorf(qx), by = floorf(qy), bz = floorf(qz);
    float fx = qx - bx, fy = qy - by, fz = qz - bz;

    unsigned ix = (unsigned)bx;
    unsigned iy = (unsigned)by;
    unsigned iz = (unsigned)bz;

    unsigned h000 = ix * P0 + iy * P1 + iz * P2;   // uint32 wraparound == numpy

    // All 8 hash addresses, then all 8 independent table loads in flight.
    int vid[8];
#pragma unroll
    for (int c = 0; c < 8; ++c) {
        unsigned cx = c & 1u;
        unsigned cy = (c >> 1) & 1u;
        unsigned cz = (c >> 2) & 1u;
        unsigned hv = (h000 + (cx ? P0 : 0u) + (cy ? P1 : 0u) + (cz ? P2 : 0u)) & BUCKETS_MASK;
        vid[c] = hash2vox[hv];
    }

    // All 8 feature loads in flight (clamped address, no branch; row 0 stays hot in L1).
    float4 f[8];
#pragma unroll
    for (int c = 0; c < 8; ++c) {
        int v = vid[c] >= 0 ? vid[c] : 0;
        f[c] = vf4[(size_t)v * 8 + dq];
    }

    float wx[2] = {1.0f - fx, fx};
    float wy[2] = {1.0f - fy, fy};
    float wz[2] = {1.0f - fz, fz};

    float ax = 0.0f, ay = 0.0f, az = 0.0f, aw = 0.0f;
#pragma unroll
    for (int c = 0; c < 8; ++c) {
        unsigned cx = c & 1u;
        unsigned cy = (c >> 1) & 1u;
        unsigned cz = (c >> 2) & 1u;
        float w = (vid[c] >= 0) ? (wx[cx] * wy[cy] * wz[cz]) : 0.0f;
        ax += f[c].x * w;
        ay += f[c].y * w;
        az += f[c].z * w;
        aw += f[c].w * w;
    }

    float4 r; r.x = ax; r.y = ay; r.z = az; r.w = aw;
    out4[(size_t)pt * 8 + dq] = r;
}

extern "C" void kernel_launch(void* const* d_in, const int* in_sizes, int n_in,
                              void* d_out, int out_size, void* d_ws, size_t ws_size,
                              hipStream_t stream) {
    const float* pts      = (const float*)d_in[0];
    const float4* vf4     = (const float4*)d_in[1];
    const int*   hash2vox = (const int*)d_in[2];
    const float* smin     = (const float*)d_in[3];
    float4* out4 = (float4*)d_out;

    int n_pts = in_sizes[0] / 3;
    int total_threads = n_pts * 8;
    int block = 256;
    int grid = (total_threads + block - 1) / block;

    infer_hashgrid_kernel<<<grid, block, 0, stream>>>(pts, vf4, hash2vox, smin, out4, n_pts);
}

// Round 4
// 74.939 us; speedup vs baseline: 1.7317x; 1.0248x over previous
//
#include <hip/hip_runtime.h>

#define BUCKETS_MASK ((1u << 21) - 1u)
#define RES_F 0.025f

typedef float f4 __attribute__((ext_vector_type(4)));   // native vector: ok for nontemporal builtins

__global__ __launch_bounds__(256) void infer_hashgrid_kernel(
    const float* __restrict__ pts,
    const f4* __restrict__ vf4,         // voxel_features viewed as [V][8] f4
    const int* __restrict__ hash2vox,
    const float* __restrict__ smin,
    f4* __restrict__ out4,              // out viewed as [N][8] f4
    int n_half)                         // n_pts / 2
{
    const unsigned P0 = 1u, P1 = 2654435761u, P2 = 805459861u;

    int tid = blockIdx.x * blockDim.x + threadIdx.x;
    int g  = tid >> 3;          // point-pair index
    int dq = tid & 7;           // which f4 of the 32-dim feature row
    if (g >= n_half) return;

    int pa = g;                 // point A
    int pb = g + n_half;        // point B (keeps per-wave stores contiguous)

    float sx = smin[0], sy = smin[1], sz = smin[2];

    float pax = __builtin_nontemporal_load(&pts[pa * 3 + 0]);
    float pay = __builtin_nontemporal_load(&pts[pa * 3 + 1]);
    float paz = __builtin_nontemporal_load(&pts[pa * 3 + 2]);
    float pbx = __builtin_nontemporal_load(&pts[pb * 3 + 0]);
    float pby = __builtin_nontemporal_load(&pts[pb * 3 + 1]);
    float pbz = __builtin_nontemporal_load(&pts[pb * 3 + 2]);

    // IEEE float32 division to bit-match numpy's (pts - smin)/RES before floor
    float qax = (pax - sx) / RES_F, qay = (pay - sy) / RES_F, qaz = (paz - sz) / RES_F;
    float qbx = (pbx - sx) / RES_F, qby = (pby - sy) / RES_F, qbz = (pbz - sz) / RES_F;

    float bax = floorf(qax), bay = floorf(qay), baz = floorf(qaz);
    float bbx = floorf(qbx), bby = floorf(qby), bbz = floorf(qbz);
    float fax = qax - bax, fay = qay - bay, faz = qaz - baz;
    float fbx = qbx - bbx, fby = qby - bby, fbz = qbz - bbz;

    unsigned ha = (unsigned)bax * P0 + (unsigned)bay * P1 + (unsigned)baz * P2;
    unsigned hb = (unsigned)bbx * P0 + (unsigned)bby * P1 + (unsigned)bbz * P2;

    // All 16 hash-table loads in flight.
    int vida[8], vidb[8];
#pragma unroll
    for (int c = 0; c < 8; ++c) {
        unsigned cx = c & 1u, cy = (c >> 1) & 1u, cz = (c >> 2) & 1u;
        unsigned dh = (cx ? P0 : 0u) + (cy ? P1 : 0u) + (cz ? P2 : 0u);
        vida[c] = hash2vox[(ha + dh) & BUCKETS_MASK];
        vidb[c] = hash2vox[(hb + dh) & BUCKETS_MASK];
    }

    // All 16 feature gathers in flight (clamped address, no branch).
    f4 fa[8], fb[8];
#pragma unroll
    for (int c = 0; c < 8; ++c) {
        int va = vida[c] >= 0 ? vida[c] : 0;
        int vb = vidb[c] >= 0 ? vidb[c] : 0;
        fa[c] = vf4[(size_t)va * 8 + dq];
        fb[c] = vf4[(size_t)vb * 8 + dq];
    }

    float wax[2] = {1.0f - fax, fax}, way[2] = {1.0f - fay, fay}, waz[2] = {1.0f - faz, faz};
    float wbx[2] = {1.0f - fbx, fbx}, wby[2] = {1.0f - fby, fby}, wbz[2] = {1.0f - fbz, fbz};

    f4 ra = {0.f, 0.f, 0.f, 0.f};
    f4 rb = {0.f, 0.f, 0.f, 0.f};
#pragma unroll
    for (int c = 0; c < 8; ++c) {
        unsigned cx = c & 1u, cy = (c >> 1) & 1u, cz = (c >> 2) & 1u;
        float wa = (vida[c] >= 0) ? (wax[cx] * way[cy] * waz[cz]) : 0.0f;
        float wb = (vidb[c] >= 0) ? (wbx[cx] * wby[cy] * wbz[cz]) : 0.0f;
        ra += fa[c] * wa;
        rb += fb[c] * wb;
    }

    // Write-once output: nontemporal so the 64MB stream doesn't thrash L3.
    __builtin_nontemporal_store(ra, &out4[(size_t)pa * 8 + dq]);
    __builtin_nontemporal_store(rb, &out4[(size_t)pb * 8 + dq]);
}

extern "C" void kernel_launch(void* const* d_in, const int* in_sizes, int n_in,
                              void* d_out, int out_size, void* d_ws, size_t ws_size,
                              hipStream_t stream) {
    const float* pts      = (const float*)d_in[0];
    const f4*    vf4      = (const f4*)d_in[1];
    const int*   hash2vox = (const int*)d_in[2];
    const float* smin     = (const float*)d_in[3];
    f4* out4 = (f4*)d_out;

    int n_pts = in_sizes[0] / 3;
    int n_half = n_pts / 2;
    int total_threads = n_half * 8;
    int block = 256;
    int grid = (total_threads + block - 1) / block;

    infer_hashgrid_kernel<<<grid, block, 0, stream>>>(pts, vf4, hash2vox, smin, out4, n_half);
}